// Round 13
// baseline (1750.256 us; speedup 1.0000x reference)
//
#include <hip/hip_runtime.h>
#include <math.h>

// Problem constants: B=32, S=12, N=2048, F=1, H=128, G=64, O=1, P=3
#define NB 32
#define SS 12
#define NN 2048
#define HH 128
#define GG 64
#define PP 3
#define RR (NN*NB)   // 65536 rows, node-major r = n*32 + b

typedef __attribute__((ext_vector_type(8))) _Float16 half8;  // 8 fp16 (4 VGPRs)
typedef __attribute__((ext_vector_type(4))) float f32x4;

__device__ __forceinline__ void glds16(const void* g, const void* l) {
    __builtin_amdgcn_global_load_lds(
        (const __attribute__((address_space(1))) void*)g,
        (__attribute__((address_space(3))) void*)l, 16, 0, 0);
}

// ---------------------------------------------------------------------------
// fp32 -> fp16 (RNE), 8 elems/thread
__global__ __launch_bounds__(256) void cvtadj(
    const float* __restrict__ src, _Float16* __restrict__ dst)
{
    size_t i0 = ((size_t)blockIdx.x * 256 + threadIdx.x) * 8;
    float4 v0 = *(const float4*)(src + i0);
    float4 v1 = *(const float4*)(src + i0 + 4);
    union { _Float16 h[8]; uint4 q; } H;
    H.h[0]=(_Float16)v0.x; H.h[1]=(_Float16)v0.y;
    H.h[2]=(_Float16)v0.z; H.h[3]=(_Float16)v0.w;
    H.h[4]=(_Float16)v1.x; H.h[5]=(_Float16)v1.y;
    H.h[6]=(_Float16)v1.z; H.h[7]=(_Float16)v1.w;
    *(uint4*)(dst + i0) = H.q;
}

// Encoder x -> fp16 rows [(t*32+b)][n] from x[b][t][n]. 384 blocks.
__global__ __launch_bounds__(256) void xcvt_enc(
    const float* __restrict__ x, _Float16* __restrict__ dst)
{
    const int row = blockIdx.x;            // t*32 + b
    const int t = row >> 5, b = row & 31;
    const size_t n0 = (size_t)threadIdx.x * 8;
    const float* src = x + ((size_t)b*SS + t)*NN;
    float4 v0 = *(const float4*)(src + n0);
    float4 v1 = *(const float4*)(src + n0 + 4);
    union { _Float16 h[8]; uint4 q; } H;
    H.h[0]=(_Float16)v0.x; H.h[1]=(_Float16)v0.y;
    H.h[2]=(_Float16)v0.z; H.h[3]=(_Float16)v0.w;
    H.h[4]=(_Float16)v1.x; H.h[5]=(_Float16)v1.y;
    H.h[6]=(_Float16)v1.z; H.h[7]=(_Float16)v1.w;
    *(uint4*)(dst + (size_t)row*NN + n0) = H.q;
}

// ---------------------------------------------------------------------------
// Precompute Wc[64][384] = Wg2 @ Wih and bc[384] = bg2 @ Wih + bih.
__global__ __launch_bounds__(256) void wprep(
    const float* __restrict__ Wg2, const float* __restrict__ Wih,
    const float* __restrict__ bih, const float* __restrict__ bg2,
    float* __restrict__ Wc, float* __restrict__ bc)
{
    int idx = blockIdx.x * 256 + threadIdx.x;
    if (idx < GG*384) {
        int g = idx / 384, o = idx % 384;
        float s = 0.f;
        for (int k = 0; k < HH; ++k)
            s = fmaf(Wg2[g*HH + k], Wih[k*384 + o], s);
        Wc[idx] = s;
    } else if (idx < GG*384 + 384) {
        int o = idx - GG*384;
        float s = bih[o];
        for (int k = 0; k < HH; ++k)
            s = fmaf(bg2[k], Wih[k*384 + o], s);
        bc[o] = s;
    }
}

// Wcomb[o][k] fp16 (o=0..383, k=0..191): k<64 -> Wc[k][o], else Whh[k-64][o].
__global__ __launch_bounds__(256) void wprep2(
    const float* __restrict__ Wc, const float* __restrict__ Whh,
    _Float16* __restrict__ Wcomb)
{
    int idx = blockIdx.x * 256 + threadIdx.x;
    if (idx < 384*192) {
        int o = idx / 192, k = idx % 192;
        float v = (k < 64) ? Wc[k*384 + o] : Whh[(k-64)*384 + o];
        Wcomb[idx] = (_Float16)v;
    }
}

// ---------------------------------------------------------------------------
// h1 from ax partials: H[(ty*2048 + c)][n] = fp16(relu(ax[.]*W1[g]+b1[g])),
// c = b*64+g; ax row = col_base + ty*32 + b, summed over 2 split-K partials.
__global__ __launch_bounds__(256) void h1T(
    const float* __restrict__ axpart, int col_base, size_t part_stride,
    const float* __restrict__ Wg1, const float* __restrict__ bg1,
    _Float16* __restrict__ Hh)
{
    const int c = blockIdx.x;
    const int ty = blockIdx.y;
    const int b = c >> 6, g = c & 63;
    const float w1 = Wg1[g], b1 = bg1[g];
    const size_t n0 = (size_t)threadIdx.x * 8;
    const size_t rowoff = (size_t)(col_base + ty*32 + b) * NN + n0;
    float f[8] = {0,0,0,0,0,0,0,0};
#pragma unroll
    for (int p = 0; p < 2; ++p) {
        const float4* q = (const float4*)(axpart + p*part_stride + rowoff);
        float4 v0 = q[0], v1 = q[1];
        f[0]+=v0.x; f[1]+=v0.y; f[2]+=v0.z; f[3]+=v0.w;
        f[4]+=v1.x; f[5]+=v1.y; f[6]+=v1.z; f[7]+=v1.w;
    }
    union { _Float16 h[8]; uint4 q; } H;
#pragma unroll
    for (int k = 0; k < 8; ++k)
        H.h[k] = (_Float16)fmaxf(fmaf(f[k], w1, b1), 0.f);
    *(uint4*)(Hh + ((size_t)ty*2048 + c) * NN + n0) = H.q;
}

// ---------------------------------------------------------------------------
// Plain fp16 MFMA GEMM (m97 structure): C = A @ B^T, A[m][K], B[cols][K],
// fp16 k-contiguous. 128x128 tile, BK=64, global_load_lds 16B, 16x16x32 MFMA.
#define GEMM_BODY                                                              \
    __shared__ __align__(16) _Float16 As[8192];  /* 16 tiles x (16m x 32k) */  \
    __shared__ __align__(16) _Float16 Bs[8192];                                \
    const int tid  = threadIdx.x;                                              \
    const int wv   = tid >> 6, lane = tid & 63;                                \
    const int lm   = lane & 15, lq = lane >> 4;                                \
    const int m0   = blockIdx.y * 128;                                         \
    const int n0   = blockIdx.x * 128;                                         \
    const int wm   = wv >> 1, wn = wv & 1;                                     \
    f32x4 acc[4][4];                                                           \
    _Pragma("unroll")                                                          \
    for (int i = 0; i < 4; ++i)                                                \
        _Pragma("unroll")                                                      \
        for (int j = 0; j < 4; ++j) acc[i][j] = (f32x4){0.f,0.f,0.f,0.f};      \
    const int kbeg = blockIdx.z * kchunk, kend = kbeg + kchunk;                \
    for (int k0 = kbeg; k0 < kend; k0 += 64) {                                 \
        _Pragma("unroll")                                                      \
        for (int t = 0; t < 4; ++t) {                                          \
            int tt = wv*4 + t;                                                 \
            int rt = tt >> 1, kt = tt & 1;                                     \
            glds16(Ah + (size_t)(m0 + rt*16 + lm)*2048 + k0 + kt*32 + lq*8,    \
                   &As[tt*512]);                                               \
            glds16(Bh + (size_t)(n0 + rt*16 + lm)*2048 + k0 + kt*32 + lq*8,    \
                   &Bs[tt*512]);                                               \
        }                                                                      \
        __syncthreads();                                                       \
        _Pragma("unroll")                                                      \
        for (int ks = 0; ks < 2; ++ks) {                                       \
            half8 af[4], bf[4];                                                \
            _Pragma("unroll")                                                  \
            for (int i = 0; i < 4; ++i) {                                      \
                af[i] = *(const half8*)&As[((wm*4 + i)*2 + ks)*512 + lane*8];  \
                bf[i] = *(const half8*)&Bs[((wn*4 + i)*2 + ks)*512 + lane*8];  \
            }                                                                  \
            _Pragma("unroll")                                                  \
            for (int i = 0; i < 4; ++i)                                        \
                _Pragma("unroll")                                              \
                for (int j = 0; j < 4; ++j)                                    \
                    acc[i][j] = __builtin_amdgcn_mfma_f32_16x16x32_f16(        \
                        af[i], bf[j], acc[i][j], 0, 0, 0);                     \
        }                                                                      \
        __syncthreads();                                                       \
    }

// fp16-C epilogue: C[row*ldc + col] (z-GEMM; consumed by gatemm as fp16 A).
__global__ __launch_bounds__(256) void gemm_mfma(
    const _Float16* __restrict__ Ah, const _Float16* __restrict__ Bh,
    _Float16* __restrict__ C, int ldc, int kchunk)
{
    GEMM_BODY
    // C/D layout: col = lane&15, row = (lane>>4)*4 + reg
#pragma unroll
    for (int i = 0; i < 4; ++i) {
        int row = m0 + wm*64 + i*16 + lq*4;
#pragma unroll
        for (int j = 0; j < 4; ++j) {
            int col = n0 + wn*64 + j*16 + lm;
            _Float16* cp = C + (size_t)row*ldc + col;
            cp[0*(size_t)ldc] = (_Float16)acc[i][j][0];
            cp[1*(size_t)ldc] = (_Float16)acc[i][j][1];
            cp[2*(size_t)ldc] = (_Float16)acc[i][j][2];
            cp[3*(size_t)ldc] = (_Float16)acc[i][j][3];
        }
    }
}

// fp32 partial epilogue: C[row*2048 + col] + split-K offset (decoder z).
__global__ __launch_bounds__(256) void gemm_mfma_p(
    const _Float16* __restrict__ Ah, const _Float16* __restrict__ Bh,
    float* __restrict__ Cbase, int kchunk, size_t partstride)
{
    float* C = Cbase + (size_t)blockIdx.z * partstride;
    GEMM_BODY
#pragma unroll
    for (int i = 0; i < 4; ++i) {
        int row = m0 + wm*64 + i*16 + lq*4;
#pragma unroll
        for (int j = 0; j < 4; ++j) {
            int col = n0 + wn*64 + j*16 + lm;
            float* cp = C + (size_t)row*2048 + col;
            cp[0*2048] = acc[i][j][0];
            cp[1*2048] = acc[i][j][1];
            cp[2*2048] = acc[i][j][2];
            cp[3*2048] = acc[i][j][3];
        }
    }
}

// Transposed fp32 epilogue: C[col*2048 + row], float4 per (i,j). ax = adj@X^T.
__global__ __launch_bounds__(256) void gemm_mfma_T(
    const _Float16* __restrict__ Ah, const _Float16* __restrict__ Bh,
    float* __restrict__ Cbase, int kchunk, size_t partstride)
{
    float* C = Cbase + (size_t)blockIdx.z * partstride;
    GEMM_BODY
#pragma unroll
    for (int i = 0; i < 4; ++i) {
        int row = m0 + wm*64 + i*16 + lq*4;
#pragma unroll
        for (int j = 0; j < 4; ++j) {
            int col = n0 + wn*64 + j*16 + lm;
            float4 v = {acc[i][j][0], acc[i][j][1], acc[i][j][2], acc[i][j][3]};
            *(float4*)(C + (size_t)col*2048 + row) = v;
        }
    }
}

// zsum: Z16[i] = fp16(p0[i] + p1[i]), 8 elems/thread, 2048 blocks.
__global__ __launch_bounds__(256) void zsum(
    const float* __restrict__ p0, const float* __restrict__ p1,
    _Float16* __restrict__ z)
{
    size_t i0 = ((size_t)blockIdx.x * 256 + threadIdx.x) * 8;
    float4 a0 = *(const float4*)(p0 + i0), a1 = *(const float4*)(p0 + i0 + 4);
    float4 b0 = *(const float4*)(p1 + i0), b1 = *(const float4*)(p1 + i0 + 4);
    union { _Float16 h[8]; uint4 q; } H;
    H.h[0]=(_Float16)(a0.x+b0.x); H.h[1]=(_Float16)(a0.y+b0.y);
    H.h[2]=(_Float16)(a0.z+b0.z); H.h[3]=(_Float16)(a0.w+b0.w);
    H.h[4]=(_Float16)(a1.x+b1.x); H.h[5]=(_Float16)(a1.y+b1.y);
    H.h[6]=(_Float16)(a1.z+b1.z); H.h[7]=(_Float16)(a1.w+b1.w);
    *(uint4*)(z + i0) = H.q;
}

// ---------------------------------------------------------------------------
// Fused MFMA gate kernel (round-9/11 proven v1). Per block: 64 rows
// r=(m*32+b), full 384 gate cols. A row = [z(64) | h(128)] fp16, K=192 in 6
// chunks of 32. B = Wcomb[384][192] staged per chunk. hzero=1 (first encoder
// step): h==0, so skip chunks 2-5 entirely and use hold=0 — bit-identical.
// (r10: register-persistent B @ VGPR 252 -> 1.5x slower; r12: 32-row blocks
// doubled staging -> slower. v1's 64-row point balances staging vs reads.)
__device__ __forceinline__ float sigmoidf_(float x) {
    return 1.f / (1.f + __expf(-x));
}
__global__ __launch_bounds__(256) void gatemm(
    const _Float16* __restrict__ Z16, int ldz, int zoff, int hzero,
    const _Float16* __restrict__ Wcomb,
    const float* __restrict__ bc, const float* __restrict__ bhh,
    _Float16* __restrict__ H16)          // read + in-place update (own rows)
{
    __shared__ __align__(16) _Float16 Asl[2048];    // [4 row-groups][512]
    __shared__ __align__(16) _Float16 Bsl[12288];   // [24 col-tiles][512]
    const int tid = threadIdx.x;
    const int wv = tid >> 6, lane = tid & 63;
    const int lm = lane & 15, lq = lane >> 4;
    const int r0 = blockIdx.x * 64;

    f32x4 acc_rz[16], acc_nx[8], acc_nh[8];
#pragma unroll
    for (int j = 0; j < 16; ++j) acc_rz[j] = (f32x4){0.f,0.f,0.f,0.f};
#pragma unroll
    for (int j = 0; j < 8; ++j) {
        acc_nx[j] = (f32x4){0.f,0.f,0.f,0.f};
        acc_nh[j] = (f32x4){0.f,0.f,0.f,0.f};
    }

    const int rA = r0 + wv*16 + lm;
    const int mA = rA >> 5, bA = rA & 31;
    const _Float16* zsrc = Z16 + (size_t)mA*ldz + zoff + bA*64 + lq*8;
    const _Float16* hsrc = H16 + (size_t)rA*128 + lq*8;

    const int cmax = hzero ? 2 : 6;
    for (int c = 0; c < cmax; ++c) {
        const _Float16* asrc = (c < 2) ? (zsrc + c*32) : (hsrc + (c-2)*32);
        glds16(asrc, &Asl[wv*512]);
#pragma unroll
        for (int t = 0; t < 6; ++t) {
            int j = wv*6 + t;
            glds16(Wcomb + (size_t)(j*16 + lm)*192 + c*32 + lq*8, &Bsl[j*512]);
        }
        __syncthreads();
        half8 af = *(const half8*)&Asl[wv*512 + lane*8];
#pragma unroll
        for (int j = 0; j < 16; ++j) {
            half8 bf = *(const half8*)&Bsl[j*512 + lane*8];
            acc_rz[j] = __builtin_amdgcn_mfma_f32_16x16x32_f16(
                af, bf, acc_rz[j], 0, 0, 0);
        }
        if (c < 2) {
#pragma unroll
            for (int j = 0; j < 8; ++j) {
                half8 bf = *(const half8*)&Bsl[(16+j)*512 + lane*8];
                acc_nx[j] = __builtin_amdgcn_mfma_f32_16x16x32_f16(
                    af, bf, acc_nx[j], 0, 0, 0);
            }
        } else {
#pragma unroll
            for (int j = 0; j < 8; ++j) {
                half8 bf = *(const half8*)&Bsl[(16+j)*512 + lane*8];
                acc_nh[j] = __builtin_amdgcn_mfma_f32_16x16x32_f16(
                    af, bf, acc_nh[j], 0, 0, 0);
            }
        }
        __syncthreads();
    }
    // epilogue: lane owns cols o=j*16+lm, rows r0+wv*16+lq*4+reg
#pragma unroll
    for (int j = 0; j < 8; ++j) {
        int o = j*16 + lm;
        float br  = bc[o]       + bhh[o];
        float bz  = bc[o+128]   + bhh[o+128];
        float bnx = bc[o+256];
        float bnh = bhh[o+256];
#pragma unroll
        for (int reg = 0; reg < 4; ++reg) {
            int r = r0 + wv*16 + lq*4 + reg;
            size_t idx = (size_t)r*128 + o;
            float hold = hzero ? 0.f : (float)H16[idx];
            float rg = sigmoidf_(acc_rz[j][reg] + br);
            float zg = sigmoidf_(acc_rz[j+8][reg] + bz);
            float ng = tanhf(acc_nx[j][reg] + bnx + rg*(acc_nh[j][reg] + bnh));
            H16[idx] = (_Float16)((1.f - zg)*ng + zg*hold);
        }
    }
}

// ---------------------------------------------------------------------------
// fck: s = h16[r] . W_fc + b_fc ; writes d_out[b][p][n] fp32 AND the decoder's
// next-step X row Xdh[b][n] fp16.
__global__ __launch_bounds__(256) void fck(
    const _Float16* __restrict__ h,
    const float* __restrict__ Wfc, const float* __restrict__ bfc,
    float* __restrict__ out_p,
    _Float16* __restrict__ Xdh)
{
    int w = (blockIdx.x * 256 + threadIdx.x) >> 6;
    int lane = threadIdx.x & 63;
    const _Float16* hr = h + (size_t)w*HH + lane*2;
    const float2* wf = (const float2*)Wfc;
    float2 b2 = wf[lane];
    float s = (float)hr[0]*b2.x + (float)hr[1]*b2.y;
#pragma unroll
    for (int off = 32; off; off >>= 1) s += __shfl_xor(s, off);
    if (lane == 0) {
        s += bfc[0];
        int n = w >> 5, b = w & 31;
        out_p[(size_t)b*(PP*NN) + n] = s;
        Xdh[(size_t)b*NN + n] = (_Float16)s;
    }
}

// ---------------------------------------------------------------------------
extern "C" void kernel_launch(void* const* d_in, const int* in_sizes, int n_in,
                              void* d_out, int out_size, void* d_ws, size_t ws_size,
                              hipStream_t stream)
{
    const float* x    = (const float*)d_in[0];
    const float* adj  = (const float*)d_in[1];
    const float* Wg1  = (const float*)d_in[2];
    const float* bg1  = (const float*)d_in[3];
    const float* Wg2  = (const float*)d_in[4];
    const float* bg2  = (const float*)d_in[5];
    const float* Wih  = (const float*)d_in[6];
    const float* Whh  = (const float*)d_in[7];
    const float* bih  = (const float*)d_in[8];
    const float* bhh  = (const float*)d_in[9];
    const float* Wfc  = (const float*)d_in[10];
    const float* bfc  = (const float*)d_in[11];

    float* ws = (float*)d_ws;
    float* Wc   = ws;                              // 64*384
    float* bc   = Wc + GG*384;                     // 1024 (384 used)
    float* AXe  = bc + 1024;                       // 2 partials x 384 x 2048
    float* AXd  = AXe + (size_t)2*384*NN;          // 2 partials x 128 x 2048
    _Float16* Ah    = (_Float16*)(AXd + (size_t)2*128*NN);  // 2048x2048 (8 MB)
    _Float16* Xeh   = Ah    + (size_t)NN*NN;       // 384 x 2048
    _Float16* Xdh   = Xeh   + (size_t)384*NN;      // 128 x 2048
    _Float16* Hgh   = Xdh   + (size_t)128*NN;      // 12288 x 2048 (48 MB)
    _Float16* Z16   = Hgh   + (size_t)12288*NN;    // 2048 x 24576 (96 MB)
    _Float16* H16   = Z16   + (size_t)NN*24576;    // RR*HH fp16 (16 MB) master
    _Float16* Wcomb = H16   + (size_t)RR*HH;       // 384*192
    // decoder split-K fp32 partials live in Hgh rows 2048.. (unused then)
    float* Zp = (float*)(Hgh + (size_t)2048*NN);   // 2 x 2048x2048 fp32
    // total ws use ~178 MiB

    hipMemsetAsync(Xdh + (size_t)32*NN, 0, (size_t)96*NN*sizeof(_Float16), stream);

    cvtadj<<<2048, 256, 0, stream>>>(adj, Ah);
    wprep<<<98, 256, 0, stream>>>(Wg2, Wih, bih, bg2, Wc, bc);
    wprep2<<<288, 256, 0, stream>>>(Wc, Whh, Wcomb);
    xcvt_enc<<<384, 256, 0, stream>>>(x, Xeh);
    // encoder ax = adj @ Xe^T, all 12 steps (split-K 2, transposed fp32 C)
    gemm_mfma_T<<<dim3(3, 16, 2), 256, 0, stream>>>(
        Ah, Xeh, AXe, 1024, (size_t)384*NN);

    float* outp = (float*)d_out;

    // encoder z for all 12 steps: 2 groups of 6 (N=12288 cols each)
    for (int g = 0; g < 2; ++g) {
        h1T<<<dim3(NN, 6), 256, 0, stream>>>(
            AXe, g*192, (size_t)384*NN, Wg1, bg1, Hgh);
        gemm_mfma<<<dim3(96, 16, 1), 256, 0, stream>>>(
            Ah, Hgh, Z16 + (size_t)g*12288, 24576, 2048);
    }
    // 12 GRU steps: sequential gatemm v1; step 0 skips the h-path (h==0)
    for (int t = 0; t < SS; ++t)
        gatemm<<<RR/64, 256, 0, stream>>>(
            Z16, 24576, t*2048, (t == 0) ? 1 : 0, Wcomb, bc, bhh, H16);

    // decoder
    for (int p = 0; p < PP; ++p) {
        fck<<<RR/4, 256, 0, stream>>>(H16, Wfc, bfc, outp + (size_t)p*NN, Xdh);
        if (p < PP-1) {
            gemm_mfma_T<<<dim3(1, 16, 2), 256, 0, stream>>>(
                Ah, Xdh, AXd, 1024, (size_t)128*NN);
            h1T<<<dim3(NN, 1), 256, 0, stream>>>(
                AXd, 0, (size_t)128*NN, Wg1, bg1, Hgh);
            // decoder z: split-K 2 (512 blocks, 2/CU) + fp16 combine
            gemm_mfma_p<<<dim3(16, 16, 2), 256, 0, stream>>>(
                Ah, Hgh, Zp, 1024, (size_t)NN*NN);
            zsum<<<2048, 256, 0, stream>>>(Zp, Zp + (size_t)NN*NN, Z16);
            gatemm<<<RR/64, 256, 0, stream>>>(
                Z16, 2048, 0, 0, Wcomb, bc, bhh, H16);
        }
    }
}

// Round 14
// 1219.995 us; speedup vs baseline: 1.4346x; 1.4346x over previous
//
#include <hip/hip_runtime.h>
#include <math.h>

// Problem constants: B=32, S=12, N=2048, F=1, H=128, G=64, O=1, P=3
#define NB 32
#define SS 12
#define NN 2048
#define HH 128
#define GG 64
#define PP 3
#define RR (NN*NB)   // 65536 rows, node-major r = n*32 + b

typedef __attribute__((ext_vector_type(8))) _Float16 half8;  // 8 fp16 (4 VGPRs)
typedef __attribute__((ext_vector_type(4))) float f32x4;

__device__ __forceinline__ void glds16(const void* g, const void* l) {
    __builtin_amdgcn_global_load_lds(
        (const __attribute__((address_space(1))) void*)g,
        (__attribute__((address_space(3))) void*)l, 16, 0, 0);
}

// ---------------------------------------------------------------------------
// fp32 -> fp16 (RNE), 8 elems/thread
__global__ __launch_bounds__(256) void cvtadj(
    const float* __restrict__ src, _Float16* __restrict__ dst)
{
    size_t i0 = ((size_t)blockIdx.x * 256 + threadIdx.x) * 8;
    float4 v0 = *(const float4*)(src + i0);
    float4 v1 = *(const float4*)(src + i0 + 4);
    union { _Float16 h[8]; uint4 q; } H;
    H.h[0]=(_Float16)v0.x; H.h[1]=(_Float16)v0.y;
    H.h[2]=(_Float16)v0.z; H.h[3]=(_Float16)v0.w;
    H.h[4]=(_Float16)v1.x; H.h[5]=(_Float16)v1.y;
    H.h[6]=(_Float16)v1.z; H.h[7]=(_Float16)v1.w;
    *(uint4*)(dst + i0) = H.q;
}

// Encoder x -> fp16 rows [(t*32+b)][n] from x[b][t][n]. 384 blocks.
__global__ __launch_bounds__(256) void xcvt_enc(
    const float* __restrict__ x, _Float16* __restrict__ dst)
{
    const int row = blockIdx.x;            // t*32 + b
    const int t = row >> 5, b = row & 31;
    const size_t n0 = (size_t)threadIdx.x * 8;
    const float* src = x + ((size_t)b*SS + t)*NN;
    float4 v0 = *(const float4*)(src + n0);
    float4 v1 = *(const float4*)(src + n0 + 4);
    union { _Float16 h[8]; uint4 q; } H;
    H.h[0]=(_Float16)v0.x; H.h[1]=(_Float16)v0.y;
    H.h[2]=(_Float16)v0.z; H.h[3]=(_Float16)v0.w;
    H.h[4]=(_Float16)v1.x; H.h[5]=(_Float16)v1.y;
    H.h[6]=(_Float16)v1.z; H.h[7]=(_Float16)v1.w;
    *(uint4*)(dst + (size_t)row*NN + n0) = H.q;
}

// ---------------------------------------------------------------------------
// Precompute Wc[64][384] = Wg2 @ Wih and bc[384] = bg2 @ Wih + bih.
__global__ __launch_bounds__(256) void wprep(
    const float* __restrict__ Wg2, const float* __restrict__ Wih,
    const float* __restrict__ bih, const float* __restrict__ bg2,
    float* __restrict__ Wc, float* __restrict__ bc)
{
    int idx = blockIdx.x * 256 + threadIdx.x;
    if (idx < GG*384) {
        int g = idx / 384, o = idx % 384;
        float s = 0.f;
        for (int k = 0; k < HH; ++k)
            s = fmaf(Wg2[g*HH + k], Wih[k*384 + o], s);
        Wc[idx] = s;
    } else if (idx < GG*384 + 384) {
        int o = idx - GG*384;
        float s = bih[o];
        for (int k = 0; k < HH; ++k)
            s = fmaf(bg2[k], Wih[k*384 + o], s);
        bc[o] = s;
    }
}

// Wcomb[o][k] fp16 (o=0..383, k=0..191): k<64 -> Wc[k][o], else Whh[k-64][o].
__global__ __launch_bounds__(256) void wprep2(
    const float* __restrict__ Wc, const float* __restrict__ Whh,
    _Float16* __restrict__ Wcomb)
{
    int idx = blockIdx.x * 256 + threadIdx.x;
    if (idx < 384*192) {
        int o = idx / 192, k = idx % 192;
        float v = (k < 64) ? Wc[k*384 + o] : Whh[(k-64)*384 + o];
        Wcomb[idx] = (_Float16)v;
    }
}

// ---------------------------------------------------------------------------
// h1 from ax partials: H[(ty*2048 + c)][n] = fp16(relu(ax[.]*W1[g]+b1[g])),
// c = b*64+g; ax row = col_base + ty*32 + b, summed over 2 split-K partials.
__global__ __launch_bounds__(256) void h1T(
    const float* __restrict__ axpart, int col_base, size_t part_stride,
    const float* __restrict__ Wg1, const float* __restrict__ bg1,
    _Float16* __restrict__ Hh)
{
    const int c = blockIdx.x;
    const int ty = blockIdx.y;
    const int b = c >> 6, g = c & 63;
    const float w1 = Wg1[g], b1 = bg1[g];
    const size_t n0 = (size_t)threadIdx.x * 8;
    const size_t rowoff = (size_t)(col_base + ty*32 + b) * NN + n0;
    float f[8] = {0,0,0,0,0,0,0,0};
#pragma unroll
    for (int p = 0; p < 2; ++p) {
        const float4* q = (const float4*)(axpart + p*part_stride + rowoff);
        float4 v0 = q[0], v1 = q[1];
        f[0]+=v0.x; f[1]+=v0.y; f[2]+=v0.z; f[3]+=v0.w;
        f[4]+=v1.x; f[5]+=v1.y; f[6]+=v1.z; f[7]+=v1.w;
    }
    union { _Float16 h[8]; uint4 q; } H;
#pragma unroll
    for (int k = 0; k < 8; ++k)
        H.h[k] = (_Float16)fmaxf(fmaf(f[k], w1, b1), 0.f);
    *(uint4*)(Hh + ((size_t)ty*2048 + c) * NN + n0) = H.q;
}

// ---------------------------------------------------------------------------
// Plain fp16 MFMA GEMM (m97 structure): C = A @ B^T, A[m][K], B[cols][K],
// fp16 k-contiguous. 128x128 tile, BK=64, global_load_lds 16B, 16x16x32 MFMA.
#define GEMM_BODY                                                              \
    __shared__ __align__(16) _Float16 As[8192];  /* 16 tiles x (16m x 32k) */  \
    __shared__ __align__(16) _Float16 Bs[8192];                                \
    const int tid  = threadIdx.x;                                              \
    const int wv   = tid >> 6, lane = tid & 63;                                \
    const int lm   = lane & 15, lq = lane >> 4;                                \
    const int m0   = blockIdx.y * 128;                                         \
    const int n0   = blockIdx.x * 128;                                         \
    const int wm   = wv >> 1, wn = wv & 1;                                     \
    f32x4 acc[4][4];                                                           \
    _Pragma("unroll")                                                          \
    for (int i = 0; i < 4; ++i)                                                \
        _Pragma("unroll")                                                      \
        for (int j = 0; j < 4; ++j) acc[i][j] = (f32x4){0.f,0.f,0.f,0.f};      \
    const int kbeg = blockIdx.z * kchunk, kend = kbeg + kchunk;                \
    for (int k0 = kbeg; k0 < kend; k0 += 64) {                                 \
        _Pragma("unroll")                                                      \
        for (int t = 0; t < 4; ++t) {                                          \
            int tt = wv*4 + t;                                                 \
            int rt = tt >> 1, kt = tt & 1;                                     \
            glds16(Ah + (size_t)(m0 + rt*16 + lm)*2048 + k0 + kt*32 + lq*8,    \
                   &As[tt*512]);                                               \
            glds16(Bh + (size_t)(n0 + rt*16 + lm)*2048 + k0 + kt*32 + lq*8,    \
                   &Bs[tt*512]);                                               \
        }                                                                      \
        __syncthreads();                                                       \
        _Pragma("unroll")                                                      \
        for (int ks = 0; ks < 2; ++ks) {                                       \
            half8 af[4], bf[4];                                                \
            _Pragma("unroll")                                                  \
            for (int i = 0; i < 4; ++i) {                                      \
                af[i] = *(const half8*)&As[((wm*4 + i)*2 + ks)*512 + lane*8];  \
                bf[i] = *(const half8*)&Bs[((wn*4 + i)*2 + ks)*512 + lane*8];  \
            }                                                                  \
            _Pragma("unroll")                                                  \
            for (int i = 0; i < 4; ++i)                                        \
                _Pragma("unroll")                                              \
                for (int j = 0; j < 4; ++j)                                    \
                    acc[i][j] = __builtin_amdgcn_mfma_f32_16x16x32_f16(        \
                        af[i], bf[j], acc[i][j], 0, 0, 0);                     \
        }                                                                      \
        __syncthreads();                                                       \
    }

// fp16-C epilogue: C[row*ldc + col] (z-GEMM; consumed by gatemm as fp16 A).
__global__ __launch_bounds__(256) void gemm_mfma(
    const _Float16* __restrict__ Ah, const _Float16* __restrict__ Bh,
    _Float16* __restrict__ C, int ldc, int kchunk)
{
    GEMM_BODY
    // C/D layout: col = lane&15, row = (lane>>4)*4 + reg
#pragma unroll
    for (int i = 0; i < 4; ++i) {
        int row = m0 + wm*64 + i*16 + lq*4;
#pragma unroll
        for (int j = 0; j < 4; ++j) {
            int col = n0 + wn*64 + j*16 + lm;
            _Float16* cp = C + (size_t)row*ldc + col;
            cp[0*(size_t)ldc] = (_Float16)acc[i][j][0];
            cp[1*(size_t)ldc] = (_Float16)acc[i][j][1];
            cp[2*(size_t)ldc] = (_Float16)acc[i][j][2];
            cp[3*(size_t)ldc] = (_Float16)acc[i][j][3];
        }
    }
}

// fp32 partial epilogue: C[row*2048 + col] + split-K offset (decoder z).
__global__ __launch_bounds__(256) void gemm_mfma_p(
    const _Float16* __restrict__ Ah, const _Float16* __restrict__ Bh,
    float* __restrict__ Cbase, int kchunk, size_t partstride)
{
    float* C = Cbase + (size_t)blockIdx.z * partstride;
    GEMM_BODY
#pragma unroll
    for (int i = 0; i < 4; ++i) {
        int row = m0 + wm*64 + i*16 + lq*4;
#pragma unroll
        for (int j = 0; j < 4; ++j) {
            int col = n0 + wn*64 + j*16 + lm;
            float* cp = C + (size_t)row*2048 + col;
            cp[0*2048] = acc[i][j][0];
            cp[1*2048] = acc[i][j][1];
            cp[2*2048] = acc[i][j][2];
            cp[3*2048] = acc[i][j][3];
        }
    }
}

// Transposed fp32 epilogue: C[col*2048 + row], float4 per (i,j). ax = adj@X^T.
__global__ __launch_bounds__(256) void gemm_mfma_T(
    const _Float16* __restrict__ Ah, const _Float16* __restrict__ Bh,
    float* __restrict__ Cbase, int kchunk, size_t partstride)
{
    float* C = Cbase + (size_t)blockIdx.z * partstride;
    GEMM_BODY
#pragma unroll
    for (int i = 0; i < 4; ++i) {
        int row = m0 + wm*64 + i*16 + lq*4;
#pragma unroll
        for (int j = 0; j < 4; ++j) {
            int col = n0 + wn*64 + j*16 + lm;
            float4 v = {acc[i][j][0], acc[i][j][1], acc[i][j][2], acc[i][j][3]};
            *(float4*)(C + (size_t)col*2048 + row) = v;
        }
    }
}

// zsum: Z16[i] = fp16(p0[i] + p1[i]), 8 elems/thread, 2048 blocks.
__global__ __launch_bounds__(256) void zsum(
    const float* __restrict__ p0, const float* __restrict__ p1,
    _Float16* __restrict__ z)
{
    size_t i0 = ((size_t)blockIdx.x * 256 + threadIdx.x) * 8;
    float4 a0 = *(const float4*)(p0 + i0), a1 = *(const float4*)(p0 + i0 + 4);
    float4 b0 = *(const float4*)(p1 + i0), b1 = *(const float4*)(p1 + i0 + 4);
    union { _Float16 h[8]; uint4 q; } H;
    H.h[0]=(_Float16)(a0.x+b0.x); H.h[1]=(_Float16)(a0.y+b0.y);
    H.h[2]=(_Float16)(a0.z+b0.z); H.h[3]=(_Float16)(a0.w+b0.w);
    H.h[4]=(_Float16)(a1.x+b1.x); H.h[5]=(_Float16)(a1.y+b1.y);
    H.h[6]=(_Float16)(a1.z+b1.z); H.h[7]=(_Float16)(a1.w+b1.w);
    *(uint4*)(z + i0) = H.q;
}

// ---------------------------------------------------------------------------
// Fused MFMA gate kernel (round-9/11 proven v1), HZERO as a TEMPLATE param so
// both variants keep compile-time trip counts and full unrolling. (Round-13
// lesson: a runtime `cmax` bound broke unrolling and cost +35 µs/dispatch.)
// Per block: 64 rows r=(m*32+b), full 384 gate cols. A row = [z(64) | h(128)]
// fp16, K=192 in 6 chunks of 32 (HZERO=1: h==0, only the 2 z-chunks run and
// hold=0 — bit-identical to multiplying zeros). B = Wcomb[384][192].
__device__ __forceinline__ float sigmoidf_(float x) {
    return 1.f / (1.f + __expf(-x));
}
template<int HZERO>
__global__ __launch_bounds__(256) void gatemm(
    const _Float16* __restrict__ Z16, int ldz, int zoff,
    const _Float16* __restrict__ Wcomb,
    const float* __restrict__ bc, const float* __restrict__ bhh,
    _Float16* __restrict__ H16)          // read + in-place update (own rows)
{
    __shared__ __align__(16) _Float16 Asl[2048];    // [4 row-groups][512]
    __shared__ __align__(16) _Float16 Bsl[12288];   // [24 col-tiles][512]
    const int tid = threadIdx.x;
    const int wv = tid >> 6, lane = tid & 63;
    const int lm = lane & 15, lq = lane >> 4;
    const int r0 = blockIdx.x * 64;

    f32x4 acc_rz[16], acc_nx[8], acc_nh[8];
#pragma unroll
    for (int j = 0; j < 16; ++j) acc_rz[j] = (f32x4){0.f,0.f,0.f,0.f};
#pragma unroll
    for (int j = 0; j < 8; ++j) {
        acc_nx[j] = (f32x4){0.f,0.f,0.f,0.f};
        acc_nh[j] = (f32x4){0.f,0.f,0.f,0.f};
    }

    const int rA = r0 + wv*16 + lm;
    const int mA = rA >> 5, bA = rA & 31;
    const _Float16* zsrc = Z16 + (size_t)mA*ldz + zoff + bA*64 + lq*8;
    const _Float16* hsrc = H16 + (size_t)rA*128 + lq*8;

    constexpr int CMAX = HZERO ? 2 : 6;
#pragma unroll
    for (int c = 0; c < CMAX; ++c) {
        const _Float16* asrc = (c < 2) ? (zsrc + c*32) : (hsrc + (c-2)*32);
        glds16(asrc, &Asl[wv*512]);
#pragma unroll
        for (int t = 0; t < 6; ++t) {
            int j = wv*6 + t;
            glds16(Wcomb + (size_t)(j*16 + lm)*192 + c*32 + lq*8, &Bsl[j*512]);
        }
        __syncthreads();
        half8 af = *(const half8*)&Asl[wv*512 + lane*8];
#pragma unroll
        for (int j = 0; j < 16; ++j) {
            half8 bf = *(const half8*)&Bsl[j*512 + lane*8];
            acc_rz[j] = __builtin_amdgcn_mfma_f32_16x16x32_f16(
                af, bf, acc_rz[j], 0, 0, 0);
        }
        if (c < 2) {
#pragma unroll
            for (int j = 0; j < 8; ++j) {
                half8 bf = *(const half8*)&Bsl[(16+j)*512 + lane*8];
                acc_nx[j] = __builtin_amdgcn_mfma_f32_16x16x32_f16(
                    af, bf, acc_nx[j], 0, 0, 0);
            }
        } else {
#pragma unroll
            for (int j = 0; j < 8; ++j) {
                half8 bf = *(const half8*)&Bsl[(16+j)*512 + lane*8];
                acc_nh[j] = __builtin_amdgcn_mfma_f32_16x16x32_f16(
                    af, bf, acc_nh[j], 0, 0, 0);
            }
        }
        __syncthreads();
    }
    // epilogue: lane owns cols o=j*16+lm, rows r0+wv*16+lq*4+reg
#pragma unroll
    for (int j = 0; j < 8; ++j) {
        int o = j*16 + lm;
        float br  = bc[o]       + bhh[o];
        float bz  = bc[o+128]   + bhh[o+128];
        float bnx = bc[o+256];
        float bnh = bhh[o+256];
#pragma unroll
        for (int reg = 0; reg < 4; ++reg) {
            int r = r0 + wv*16 + lq*4 + reg;
            size_t idx = (size_t)r*128 + o;
            float hold = HZERO ? 0.f : (float)H16[idx];
            float rg = sigmoidf_(acc_rz[j][reg] + br);
            float zg = sigmoidf_(acc_rz[j+8][reg] + bz);
            float ng = tanhf(acc_nx[j][reg] + bnx + rg*(acc_nh[j][reg] + bnh));
            H16[idx] = (_Float16)((1.f - zg)*ng + zg*hold);
        }
    }
}

// ---------------------------------------------------------------------------
// fck: s = h16[r] . W_fc + b_fc ; writes d_out[b][p][n] fp32 AND the decoder's
// next-step X row Xdh[b][n] fp16.
__global__ __launch_bounds__(256) void fck(
    const _Float16* __restrict__ h,
    const float* __restrict__ Wfc, const float* __restrict__ bfc,
    float* __restrict__ out_p,
    _Float16* __restrict__ Xdh)
{
    int w = (blockIdx.x * 256 + threadIdx.x) >> 6;
    int lane = threadIdx.x & 63;
    const _Float16* hr = h + (size_t)w*HH + lane*2;
    const float2* wf = (const float2*)Wfc;
    float2 b2 = wf[lane];
    float s = (float)hr[0]*b2.x + (float)hr[1]*b2.y;
#pragma unroll
    for (int off = 32; off; off >>= 1) s += __shfl_xor(s, off);
    if (lane == 0) {
        s += bfc[0];
        int n = w >> 5, b = w & 31;
        out_p[(size_t)b*(PP*NN) + n] = s;
        Xdh[(size_t)b*NN + n] = (_Float16)s;
    }
}

// ---------------------------------------------------------------------------
extern "C" void kernel_launch(void* const* d_in, const int* in_sizes, int n_in,
                              void* d_out, int out_size, void* d_ws, size_t ws_size,
                              hipStream_t stream)
{
    const float* x    = (const float*)d_in[0];
    const float* adj  = (const float*)d_in[1];
    const float* Wg1  = (const float*)d_in[2];
    const float* bg1  = (const float*)d_in[3];
    const float* Wg2  = (const float*)d_in[4];
    const float* bg2  = (const float*)d_in[5];
    const float* Wih  = (const float*)d_in[6];
    const float* Whh  = (const float*)d_in[7];
    const float* bih  = (const float*)d_in[8];
    const float* bhh  = (const float*)d_in[9];
    const float* Wfc  = (const float*)d_in[10];
    const float* bfc  = (const float*)d_in[11];

    float* ws = (float*)d_ws;
    float* Wc   = ws;                              // 64*384
    float* bc   = Wc + GG*384;                     // 1024 (384 used)
    float* AXe  = bc + 1024;                       // 2 partials x 384 x 2048
    float* AXd  = AXe + (size_t)2*384*NN;          // 2 partials x 128 x 2048
    _Float16* Ah    = (_Float16*)(AXd + (size_t)2*128*NN);  // 2048x2048 (8 MB)
    _Float16* Xeh   = Ah    + (size_t)NN*NN;       // 384 x 2048
    _Float16* Xdh   = Xeh   + (size_t)384*NN;      // 128 x 2048
    _Float16* Hgh   = Xdh   + (size_t)128*NN;      // 12288 x 2048 (48 MB)
    _Float16* Z16   = Hgh   + (size_t)12288*NN;    // 2048 x 24576 (96 MB)
    _Float16* H16   = Z16   + (size_t)NN*24576;    // RR*HH fp16 (16 MB) master
    _Float16* Wcomb = H16   + (size_t)RR*HH;       // 384*192
    // decoder split-K fp32 partials live in Hgh rows 2048.. (unused then)
    float* Zp = (float*)(Hgh + (size_t)2048*NN);   // 2 x 2048x2048 fp32
    // total ws use ~178 MiB

    hipMemsetAsync(Xdh + (size_t)32*NN, 0, (size_t)96*NN*sizeof(_Float16), stream);

    cvtadj<<<2048, 256, 0, stream>>>(adj, Ah);
    wprep<<<98, 256, 0, stream>>>(Wg2, Wih, bih, bg2, Wc, bc);
    wprep2<<<288, 256, 0, stream>>>(Wc, Whh, Wcomb);
    xcvt_enc<<<384, 256, 0, stream>>>(x, Xeh);
    // encoder ax = adj @ Xe^T, all 12 steps (split-K 2, transposed fp32 C)
    gemm_mfma_T<<<dim3(3, 16, 2), 256, 0, stream>>>(
        Ah, Xeh, AXe, 1024, (size_t)384*NN);

    float* outp = (float*)d_out;

    // encoder z for all 12 steps: 2 groups of 6 (N=12288 cols each)
    for (int g = 0; g < 2; ++g) {
        h1T<<<dim3(NN, 6), 256, 0, stream>>>(
            AXe, g*192, (size_t)384*NN, Wg1, bg1, Hgh);
        gemm_mfma<<<dim3(96, 16, 1), 256, 0, stream>>>(
            Ah, Hgh, Z16 + (size_t)g*12288, 24576, 2048);
    }
    // 12 GRU steps: gatemm v1; step 0 uses the HZERO=1 instantiation (h==0)
    gatemm<1><<<RR/64, 256, 0, stream>>>(
        Z16, 24576, 0, Wcomb, bc, bhh, H16);
    for (int t = 1; t < SS; ++t)
        gatemm<0><<<RR/64, 256, 0, stream>>>(
            Z16, 24576, t*2048, Wcomb, bc, bhh, H16);

    // decoder
    for (int p = 0; p < PP; ++p) {
        fck<<<RR/4, 256, 0, stream>>>(H16, Wfc, bfc, outp + (size_t)p*NN, Xdh);
        if (p < PP-1) {
            gemm_mfma_T<<<dim3(1, 16, 2), 256, 0, stream>>>(
                Ah, Xdh, AXd, 1024, (size_t)128*NN);
            h1T<<<dim3(NN, 1), 256, 0, stream>>>(
                AXd, 0, (size_t)128*NN, Wg1, bg1, Hgh);
            // decoder z: split-K 2 (512 blocks, 2/CU) + fp16 combine
            gemm_mfma_p<<<dim3(16, 16, 2), 256, 0, stream>>>(
                Ah, Hgh, Zp, 1024, (size_t)NN*NN);
            zsum<<<2048, 256, 0, stream>>>(Zp, Zp + (size_t)NN*NN, Z16);
            gatemm<0><<<RR/64, 256, 0, stream>>>(
                Z16, 2048, 0, Wcomb, bc, bhh, H16);
        }
    }
}

// Round 15
// 1205.973 us; speedup vs baseline: 1.4513x; 1.0116x over previous
//
#include <hip/hip_runtime.h>
#include <math.h>

// Problem constants: B=32, S=12, N=2048, F=1, H=128, G=64, O=1, P=3
#define NB 32
#define SS 12
#define NN 2048
#define HH 128
#define GG 64
#define PP 3
#define RR (NN*NB)   // 65536 rows, node-major r = n*32 + b

typedef __attribute__((ext_vector_type(8))) _Float16 half8;  // 8 fp16 (4 VGPRs)
typedef __attribute__((ext_vector_type(4))) float f32x4;

__device__ __forceinline__ void glds16(const void* g, const void* l) {
    __builtin_amdgcn_global_load_lds(
        (const __attribute__((address_space(1))) void*)g,
        (__attribute__((address_space(3))) void*)l, 16, 0, 0);
}

// ---------------------------------------------------------------------------
// fp32 -> fp16 (RNE), 8 elems/thread
__global__ __launch_bounds__(256) void cvtadj(
    const float* __restrict__ src, _Float16* __restrict__ dst)
{
    size_t i0 = ((size_t)blockIdx.x * 256 + threadIdx.x) * 8;
    float4 v0 = *(const float4*)(src + i0);
    float4 v1 = *(const float4*)(src + i0 + 4);
    union { _Float16 h[8]; uint4 q; } H;
    H.h[0]=(_Float16)v0.x; H.h[1]=(_Float16)v0.y;
    H.h[2]=(_Float16)v0.z; H.h[3]=(_Float16)v0.w;
    H.h[4]=(_Float16)v1.x; H.h[5]=(_Float16)v1.y;
    H.h[6]=(_Float16)v1.z; H.h[7]=(_Float16)v1.w;
    *(uint4*)(dst + i0) = H.q;
}

// Encoder x -> fp16 rows [(t*32+b)][n] from x[b][t][n]. 384 blocks.
__global__ __launch_bounds__(256) void xcvt_enc(
    const float* __restrict__ x, _Float16* __restrict__ dst)
{
    const int row = blockIdx.x;            // t*32 + b
    const int t = row >> 5, b = row & 31;
    const size_t n0 = (size_t)threadIdx.x * 8;
    const float* src = x + ((size_t)b*SS + t)*NN;
    float4 v0 = *(const float4*)(src + n0);
    float4 v1 = *(const float4*)(src + n0 + 4);
    union { _Float16 h[8]; uint4 q; } H;
    H.h[0]=(_Float16)v0.x; H.h[1]=(_Float16)v0.y;
    H.h[2]=(_Float16)v0.z; H.h[3]=(_Float16)v0.w;
    H.h[4]=(_Float16)v1.x; H.h[5]=(_Float16)v1.y;
    H.h[6]=(_Float16)v1.z; H.h[7]=(_Float16)v1.w;
    *(uint4*)(dst + (size_t)row*NN + n0) = H.q;
}

// ---------------------------------------------------------------------------
// Precompute Wc[64][384] = Wg2 @ Wih and bc[384] = bg2 @ Wih + bih.
__global__ __launch_bounds__(256) void wprep(
    const float* __restrict__ Wg2, const float* __restrict__ Wih,
    const float* __restrict__ bih, const float* __restrict__ bg2,
    float* __restrict__ Wc, float* __restrict__ bc)
{
    int idx = blockIdx.x * 256 + threadIdx.x;
    if (idx < GG*384) {
        int g = idx / 384, o = idx % 384;
        float s = 0.f;
        for (int k = 0; k < HH; ++k)
            s = fmaf(Wg2[g*HH + k], Wih[k*384 + o], s);
        Wc[idx] = s;
    } else if (idx < GG*384 + 384) {
        int o = idx - GG*384;
        float s = bih[o];
        for (int k = 0; k < HH; ++k)
            s = fmaf(bg2[k], Wih[k*384 + o], s);
        bc[o] = s;
    }
}

// Wcomb[o][k] fp16 (o=0..383, k=0..191): k<64 -> Wc[k][o], else Whh[k-64][o].
__global__ __launch_bounds__(256) void wprep2(
    const float* __restrict__ Wc, const float* __restrict__ Whh,
    _Float16* __restrict__ Wcomb)
{
    int idx = blockIdx.x * 256 + threadIdx.x;
    if (idx < 384*192) {
        int o = idx / 192, k = idx % 192;
        float v = (k < 64) ? Wc[k*384 + o] : Whh[(k-64)*384 + o];
        Wcomb[idx] = (_Float16)v;
    }
}

// ---------------------------------------------------------------------------
// h1 from ax partials: H[(ty*2048 + c)][n] = fp16(relu(ax[.]*W1[g]+b1[g])),
// c = b*64+g; ax row = col_base + ty*32 + b, summed over 2 split-K partials.
__global__ __launch_bounds__(256) void h1T(
    const float* __restrict__ axpart, int col_base, size_t part_stride,
    const float* __restrict__ Wg1, const float* __restrict__ bg1,
    _Float16* __restrict__ Hh)
{
    const int c = blockIdx.x;
    const int ty = blockIdx.y;
    const int b = c >> 6, g = c & 63;
    const float w1 = Wg1[g], b1 = bg1[g];
    const size_t n0 = (size_t)threadIdx.x * 8;
    const size_t rowoff = (size_t)(col_base + ty*32 + b) * NN + n0;
    float f[8] = {0,0,0,0,0,0,0,0};
#pragma unroll
    for (int p = 0; p < 2; ++p) {
        const float4* q = (const float4*)(axpart + p*part_stride + rowoff);
        float4 v0 = q[0], v1 = q[1];
        f[0]+=v0.x; f[1]+=v0.y; f[2]+=v0.z; f[3]+=v0.w;
        f[4]+=v1.x; f[5]+=v1.y; f[6]+=v1.z; f[7]+=v1.w;
    }
    union { _Float16 h[8]; uint4 q; } H;
#pragma unroll
    for (int k = 0; k < 8; ++k)
        H.h[k] = (_Float16)fmaxf(fmaf(f[k], w1, b1), 0.f);
    *(uint4*)(Hh + ((size_t)ty*2048 + c) * NN + n0) = H.q;
}

// ---------------------------------------------------------------------------
// Plain fp16 MFMA GEMM (m97 structure): C = A @ B^T, A[m][K], B[cols][K],
// fp16 k-contiguous. 128x128 tile, BK=64, global_load_lds 16B, 16x16x32 MFMA.
#define GEMM_BODY                                                              \
    __shared__ __align__(16) _Float16 As[8192];  /* 16 tiles x (16m x 32k) */  \
    __shared__ __align__(16) _Float16 Bs[8192];                                \
    const int tid  = threadIdx.x;                                              \
    const int wv   = tid >> 6, lane = tid & 63;                                \
    const int lm   = lane & 15, lq = lane >> 4;                                \
    const int m0   = blockIdx.y * 128;                                         \
    const int n0   = blockIdx.x * 128;                                         \
    const int wm   = wv >> 1, wn = wv & 1;                                     \
    f32x4 acc[4][4];                                                           \
    _Pragma("unroll")                                                          \
    for (int i = 0; i < 4; ++i)                                                \
        _Pragma("unroll")                                                      \
        for (int j = 0; j < 4; ++j) acc[i][j] = (f32x4){0.f,0.f,0.f,0.f};      \
    const int kbeg = blockIdx.z * kchunk, kend = kbeg + kchunk;                \
    for (int k0 = kbeg; k0 < kend; k0 += 64) {                                 \
        _Pragma("unroll")                                                      \
        for (int t = 0; t < 4; ++t) {                                          \
            int tt = wv*4 + t;                                                 \
            int rt = tt >> 1, kt = tt & 1;                                     \
            glds16(Ah + (size_t)(m0 + rt*16 + lm)*2048 + k0 + kt*32 + lq*8,    \
                   &As[tt*512]);                                               \
            glds16(Bh + (size_t)(n0 + rt*16 + lm)*2048 + k0 + kt*32 + lq*8,    \
                   &Bs[tt*512]);                                               \
        }                                                                      \
        __syncthreads();                                                       \
        _Pragma("unroll")                                                      \
        for (int ks = 0; ks < 2; ++ks) {                                       \
            half8 af[4], bf[4];                                                \
            _Pragma("unroll")                                                  \
            for (int i = 0; i < 4; ++i) {                                      \
                af[i] = *(const half8*)&As[((wm*4 + i)*2 + ks)*512 + lane*8];  \
                bf[i] = *(const half8*)&Bs[((wn*4 + i)*2 + ks)*512 + lane*8];  \
            }                                                                  \
            _Pragma("unroll")                                                  \
            for (int i = 0; i < 4; ++i)                                        \
                _Pragma("unroll")                                              \
                for (int j = 0; j < 4; ++j)                                    \
                    acc[i][j] = __builtin_amdgcn_mfma_f32_16x16x32_f16(        \
                        af[i], bf[j], acc[i][j], 0, 0, 0);                     \
        }                                                                      \
        __syncthreads();                                                       \
    }

// fp16-C epilogue: C[row*ldc + col] (z-GEMM; consumed by gatemm as fp16 A).
__global__ __launch_bounds__(256) void gemm_mfma(
    const _Float16* __restrict__ Ah, const _Float16* __restrict__ Bh,
    _Float16* __restrict__ C, int ldc, int kchunk)
{
    GEMM_BODY
    // C/D layout: col = lane&15, row = (lane>>4)*4 + reg
#pragma unroll
    for (int i = 0; i < 4; ++i) {
        int row = m0 + wm*64 + i*16 + lq*4;
#pragma unroll
        for (int j = 0; j < 4; ++j) {
            int col = n0 + wn*64 + j*16 + lm;
            _Float16* cp = C + (size_t)row*ldc + col;
            cp[0*(size_t)ldc] = (_Float16)acc[i][j][0];
            cp[1*(size_t)ldc] = (_Float16)acc[i][j][1];
            cp[2*(size_t)ldc] = (_Float16)acc[i][j][2];
            cp[3*(size_t)ldc] = (_Float16)acc[i][j][3];
        }
    }
}

// fp32 partial epilogue: C[row*2048 + col] + split-K offset (decoder z).
__global__ __launch_bounds__(256) void gemm_mfma_p(
    const _Float16* __restrict__ Ah, const _Float16* __restrict__ Bh,
    float* __restrict__ Cbase, int kchunk, size_t partstride)
{
    float* C = Cbase + (size_t)blockIdx.z * partstride;
    GEMM_BODY
#pragma unroll
    for (int i = 0; i < 4; ++i) {
        int row = m0 + wm*64 + i*16 + lq*4;
#pragma unroll
        for (int j = 0; j < 4; ++j) {
            int col = n0 + wn*64 + j*16 + lm;
            float* cp = C + (size_t)row*2048 + col;
            cp[0*2048] = acc[i][j][0];
            cp[1*2048] = acc[i][j][1];
            cp[2*2048] = acc[i][j][2];
            cp[3*2048] = acc[i][j][3];
        }
    }
}

// Transposed fp32 epilogue: C[col*2048 + row], float4 per (i,j). ax = adj@X^T.
__global__ __launch_bounds__(256) void gemm_mfma_T(
    const _Float16* __restrict__ Ah, const _Float16* __restrict__ Bh,
    float* __restrict__ Cbase, int kchunk, size_t partstride)
{
    float* C = Cbase + (size_t)blockIdx.z * partstride;
    GEMM_BODY
#pragma unroll
    for (int i = 0; i < 4; ++i) {
        int row = m0 + wm*64 + i*16 + lq*4;
#pragma unroll
        for (int j = 0; j < 4; ++j) {
            int col = n0 + wn*64 + j*16 + lm;
            float4 v = {acc[i][j][0], acc[i][j][1], acc[i][j][2], acc[i][j][3]};
            *(float4*)(C + (size_t)col*2048 + row) = v;
        }
    }
}

// zsum: Z16[i] = fp16(p0[i] + p1[i]), 8 elems/thread, 2048 blocks.
__global__ __launch_bounds__(256) void zsum(
    const float* __restrict__ p0, const float* __restrict__ p1,
    _Float16* __restrict__ z)
{
    size_t i0 = ((size_t)blockIdx.x * 256 + threadIdx.x) * 8;
    float4 a0 = *(const float4*)(p0 + i0), a1 = *(const float4*)(p0 + i0 + 4);
    float4 b0 = *(const float4*)(p1 + i0), b1 = *(const float4*)(p1 + i0 + 4);
    union { _Float16 h[8]; uint4 q; } H;
    H.h[0]=(_Float16)(a0.x+b0.x); H.h[1]=(_Float16)(a0.y+b0.y);
    H.h[2]=(_Float16)(a0.z+b0.z); H.h[3]=(_Float16)(a0.w+b0.w);
    H.h[4]=(_Float16)(a1.x+b1.x); H.h[5]=(_Float16)(a1.y+b1.y);
    H.h[6]=(_Float16)(a1.z+b1.z); H.h[7]=(_Float16)(a1.w+b1.w);
    *(uint4*)(z + i0) = H.q;
}

// ---------------------------------------------------------------------------
// Fused MFMA gate kernel v3: 64-row block (round-9 staging, unchanged), but
// compute mapping partitions COL-tiles across waves with the interleave
// jt = w + 4*ct (round-10-verified): wave w owns r-tiles {w, w+4},
// z-tiles {8+w, 8+w+4}, n-tiles {16+w, 16+w+4} -> wave-local epilogue.
// Each wave reads all 4 A row-groups instead of all 24 B tiles:
// 10 ds_read_b128 per chunk per wave (vs 25 in v1) for the same 24 MFMA —
// v1 was LDS-read-issue-bound (~12 of 26 µs in ds_read cycles).
// Per-accumulator MFMA sequence identical to v1 -> bit-identical output.
__device__ __forceinline__ float sigmoidf_(float x) {
    return 1.f / (1.f + __expf(-x));
}
template<int HZERO>
__global__ __launch_bounds__(256) void gatemm(
    const _Float16* __restrict__ Z16, int ldz, int zoff,
    const _Float16* __restrict__ Wcomb,
    const float* __restrict__ bc, const float* __restrict__ bhh,
    _Float16* __restrict__ H16)          // read + in-place update (own rows)
{
    __shared__ __align__(16) _Float16 Asl[2048];    // [4 row-groups][512]
    __shared__ __align__(16) _Float16 Bsl[12288];   // [24 col-tiles][512]
    const int tid = threadIdx.x;
    const int w = tid >> 6, lane = tid & 63;
    const int lm = lane & 15, lq = lane >> 4;
    const int r0 = blockIdx.x * 64;

    f32x4 acc_r[4][2], acc_z[4][2], acc_nx[4][2], acc_nh[4][2];
#pragma unroll
    for (int rt = 0; rt < 4; ++rt)
#pragma unroll
        for (int ct = 0; ct < 2; ++ct) {
            acc_r[rt][ct]  = (f32x4){0.f,0.f,0.f,0.f};
            acc_z[rt][ct]  = (f32x4){0.f,0.f,0.f,0.f};
            acc_nx[rt][ct] = (f32x4){0.f,0.f,0.f,0.f};
            acc_nh[rt][ct] = (f32x4){0.f,0.f,0.f,0.f};
        }

    // staging (unchanged from v1): wave w stages A row-group w + B tiles w*6+t
    const int rA = r0 + w*16 + lm;
    const int mA = rA >> 5, bA = rA & 31;
    const _Float16* zsrc = Z16 + (size_t)mA*ldz + zoff + bA*64 + lq*8;
    const _Float16* hsrc = H16 + (size_t)rA*128 + lq*8;

    constexpr int CMAX = HZERO ? 2 : 6;
#pragma unroll
    for (int c = 0; c < CMAX; ++c) {
        const _Float16* asrc = (c < 2) ? (zsrc + c*32) : (hsrc + (c-2)*32);
        glds16(asrc, &Asl[w*512]);
#pragma unroll
        for (int t = 0; t < 6; ++t) {
            int j = w*6 + t;
            glds16(Wcomb + (size_t)(j*16 + lm)*192 + c*32 + lq*8, &Bsl[j*512]);
        }
        __syncthreads();
        half8 af[4];
#pragma unroll
        for (int rt = 0; rt < 4; ++rt)
            af[rt] = *(const half8*)&Asl[rt*512 + lane*8];
#pragma unroll
        for (int ct = 0; ct < 2; ++ct) {
            half8 bfr = *(const half8*)&Bsl[(w + 4*ct)*512 + lane*8];
            half8 bfz = *(const half8*)&Bsl[(8 + w + 4*ct)*512 + lane*8];
            half8 bfn = *(const half8*)&Bsl[(16 + w + 4*ct)*512 + lane*8];
#pragma unroll
            for (int rt = 0; rt < 4; ++rt) {
                acc_r[rt][ct] = __builtin_amdgcn_mfma_f32_16x16x32_f16(
                    af[rt], bfr, acc_r[rt][ct], 0, 0, 0);
                acc_z[rt][ct] = __builtin_amdgcn_mfma_f32_16x16x32_f16(
                    af[rt], bfz, acc_z[rt][ct], 0, 0, 0);
                if (c < 2)
                    acc_nx[rt][ct] = __builtin_amdgcn_mfma_f32_16x16x32_f16(
                        af[rt], bfn, acc_nx[rt][ct], 0, 0, 0);
                else
                    acc_nh[rt][ct] = __builtin_amdgcn_mfma_f32_16x16x32_f16(
                        af[rt], bfn, acc_nh[rt][ct], 0, 0, 0);
            }
        }
        __syncthreads();
    }
    // epilogue: lane owns cols o=(w+4*ct)*16+lm, rows r0 + rt*16 + lq*4 + reg
#pragma unroll
    for (int ct = 0; ct < 2; ++ct) {
        int o = (w + 4*ct)*16 + lm;
        float br  = bc[o]       + bhh[o];
        float bz  = bc[o+128]   + bhh[o+128];
        float bnx = bc[o+256];
        float bnh = bhh[o+256];
#pragma unroll
        for (int rt = 0; rt < 4; ++rt) {
#pragma unroll
            for (int reg = 0; reg < 4; ++reg) {
                int r = r0 + rt*16 + lq*4 + reg;
                size_t idx = (size_t)r*128 + o;
                float hold = HZERO ? 0.f : (float)H16[idx];
                float rg = sigmoidf_(acc_r[rt][ct][reg] + br);
                float zg = sigmoidf_(acc_z[rt][ct][reg] + bz);
                float ng = tanhf(acc_nx[rt][ct][reg] + bnx
                                 + rg*(acc_nh[rt][ct][reg] + bnh));
                H16[idx] = (_Float16)((1.f - zg)*ng + zg*hold);
            }
        }
    }
}

// ---------------------------------------------------------------------------
// fck: s = h16[r] . W_fc + b_fc ; writes d_out[b][p][n] fp32 AND the decoder's
// next-step X row Xdh[b][n] fp16.
__global__ __launch_bounds__(256) void fck(
    const _Float16* __restrict__ h,
    const float* __restrict__ Wfc, const float* __restrict__ bfc,
    float* __restrict__ out_p,
    _Float16* __restrict__ Xdh)
{
    int w = (blockIdx.x * 256 + threadIdx.x) >> 6;
    int lane = threadIdx.x & 63;
    const _Float16* hr = h + (size_t)w*HH + lane*2;
    const float2* wf = (const float2*)Wfc;
    float2 b2 = wf[lane];
    float s = (float)hr[0]*b2.x + (float)hr[1]*b2.y;
#pragma unroll
    for (int off = 32; off; off >>= 1) s += __shfl_xor(s, off);
    if (lane == 0) {
        s += bfc[0];
        int n = w >> 5, b = w & 31;
        out_p[(size_t)b*(PP*NN) + n] = s;
        Xdh[(size_t)b*NN + n] = (_Float16)s;
    }
}

// ---------------------------------------------------------------------------
extern "C" void kernel_launch(void* const* d_in, const int* in_sizes, int n_in,
                              void* d_out, int out_size, void* d_ws, size_t ws_size,
                              hipStream_t stream)
{
    const float* x    = (const float*)d_in[0];
    const float* adj  = (const float*)d_in[1];
    const float* Wg1  = (const float*)d_in[2];
    const float* bg1  = (const float*)d_in[3];
    const float* Wg2  = (const float*)d_in[4];
    const float* bg2  = (const float*)d_in[5];
    const float* Wih  = (const float*)d_in[6];
    const float* Whh  = (const float*)d_in[7];
    const float* bih  = (const float*)d_in[8];
    const float* bhh  = (const float*)d_in[9];
    const float* Wfc  = (const float*)d_in[10];
    const float* bfc  = (const float*)d_in[11];

    float* ws = (float*)d_ws;
    float* Wc   = ws;                              // 64*384
    float* bc   = Wc + GG*384;                     // 1024 (384 used)
    float* AXe  = bc + 1024;                       // 2 partials x 384 x 2048
    float* AXd  = AXe + (size_t)2*384*NN;          // 2 partials x 128 x 2048
    _Float16* Ah    = (_Float16*)(AXd + (size_t)2*128*NN);  // 2048x2048 (8 MB)
    _Float16* Xeh   = Ah    + (size_t)NN*NN;       // 384 x 2048
    _Float16* Xdh   = Xeh   + (size_t)384*NN;      // 128 x 2048
    _Float16* Hgh   = Xdh   + (size_t)128*NN;      // 12288 x 2048 (48 MB)
    _Float16* Z16   = Hgh   + (size_t)12288*NN;    // 2048 x 24576 (96 MB)
    _Float16* H16   = Z16   + (size_t)NN*24576;    // RR*HH fp16 (16 MB) master
    _Float16* Wcomb = H16   + (size_t)RR*HH;       // 384*192
    // decoder split-K fp32 partials live in Hgh rows 2048.. (unused then)
    float* Zp = (float*)(Hgh + (size_t)2048*NN);   // 2 x 2048x2048 fp32
    // total ws use ~178 MiB

    hipMemsetAsync(Xdh + (size_t)32*NN, 0, (size_t)96*NN*sizeof(_Float16), stream);

    cvtadj<<<2048, 256, 0, stream>>>(adj, Ah);
    wprep<<<98, 256, 0, stream>>>(Wg2, Wih, bih, bg2, Wc, bc);
    wprep2<<<288, 256, 0, stream>>>(Wc, Whh, Wcomb);
    xcvt_enc<<<384, 256, 0, stream>>>(x, Xeh);
    // encoder ax = adj @ Xe^T, all 12 steps (split-K 2, transposed fp32 C)
    gemm_mfma_T<<<dim3(3, 16, 2), 256, 0, stream>>>(
        Ah, Xeh, AXe, 1024, (size_t)384*NN);

    float* outp = (float*)d_out;

    // encoder z for all 12 steps: 2 groups of 6 (N=12288 cols each)
    for (int g = 0; g < 2; ++g) {
        h1T<<<dim3(NN, 6), 256, 0, stream>>>(
            AXe, g*192, (size_t)384*NN, Wg1, bg1, Hgh);
        gemm_mfma<<<dim3(96, 16, 1), 256, 0, stream>>>(
            Ah, Hgh, Z16 + (size_t)g*12288, 24576, 2048);
    }
    // 12 GRU steps: gatemm v3; step 0 uses the HZERO=1 instantiation (h==0)
    gatemm<1><<<RR/64, 256, 0, stream>>>(
        Z16, 24576, 0, Wcomb, bc, bhh, H16);
    for (int t = 1; t < SS; ++t)
        gatemm<0><<<RR/64, 256, 0, stream>>>(
            Z16, 24576, t*2048, Wcomb, bc, bhh, H16);

    // decoder
    for (int p = 0; p < PP; ++p) {
        fck<<<RR/4, 256, 0, stream>>>(H16, Wfc, bfc, outp + (size_t)p*NN, Xdh);
        if (p < PP-1) {
            gemm_mfma_T<<<dim3(1, 16, 2), 256, 0, stream>>>(
                Ah, Xdh, AXd, 1024, (size_t)128*NN);
            h1T<<<dim3(NN, 1), 256, 0, stream>>>(
                AXd, 0, (size_t)128*NN, Wg1, bg1, Hgh);
            // decoder z: split-K 2 (512 blocks, 2/CU) + fp16 combine
            gemm_mfma_p<<<dim3(16, 16, 2), 256, 0, stream>>>(
                Ah, Hgh, Zp, 1024, (size_t)NN*NN);
            zsum<<<2048, 256, 0, stream>>>(Zp, Zp + (size_t)NN*NN, Z16);
            gatemm<0><<<RR/64, 256, 0, stream>>>(
                Z16, 2048, 0, Wcomb, bc, bhh, H16);
        }
    }
}